// Round 2
// baseline (4207.901 us; speedup 1.0000x reference)
//
#include <hip/hip_runtime.h>
#include <hip/hip_bf16.h>
#include <stdint.h>
#include <stddef.h>

// Problem dims
#define BATCH 1024
#define TSEQ  99      // SEQ_LEN-1 steps
#define HID   256
#define GDIM  1024    // 4*HID
#define EDIM  128
#define VOC   410
#define NT_FC 26      // ceil(410/16) -> padded 416

typedef __attribute__((ext_vector_type(8))) short short8;
typedef __attribute__((ext_vector_type(4))) float floatx4;

#define LOG2E 1.4426950408889634f

__device__ __forceinline__ short f2bf(float x) {
    union { float f; uint32_t u; } v; v.f = x;
    uint32_t r = (v.u + 0x7fffu + ((v.u >> 16) & 1u)) >> 16;
    return (short)r;
}

__device__ __forceinline__ float fexp2(float x) {
#if __has_builtin(__builtin_amdgcn_exp2f)
    return __builtin_amdgcn_exp2f(x);
#else
    return __exp2f(x);
#endif
}
__device__ __forceinline__ float frcp(float x) {
#if __has_builtin(__builtin_amdgcn_rcpf)
    return __builtin_amdgcn_rcpf(x);
#else
    return 1.f / x;
#endif
}
__device__ __forceinline__ float sigm(float x) {
    return frcp(1.f + fexp2(-LOG2E * x));
}
__device__ __forceinline__ float tanh_fast(float x) {
    x = fminf(fmaxf(x, -16.f), 16.f);
    float t = fexp2((2.f * LOG2E) * x);
    return (t - 1.f) * frcp(t + 1.f);
}

__device__ __forceinline__ void acquire_fence_agent() {
#if __has_builtin(__builtin_amdgcn_fence)
    __builtin_amdgcn_fence(__ATOMIC_ACQUIRE, "agent");
#else
    __threadfence();
#endif
}

// ---------------------------------------------------------------------------
// enc[b][h] = b_enc[h] + sum_k encoder_out[b][k] * W_enc[h][k]
__global__ void k_enc(const float* __restrict__ x, const float* __restrict__ W,
                      const float* __restrict__ bias, float* __restrict__ enc) {
    __shared__ float xl[8 * 256];
    const int tid = threadIdx.x;
    const int b0 = blockIdx.x * 8;
#pragma unroll
    for (int i = 0; i < 8; ++i) xl[i * 256 + tid] = x[(b0 + i) * 256 + tid];
    __syncthreads();
    const int h = tid;
    float acc[8];
    const float bh = bias[h];
#pragma unroll
    for (int i = 0; i < 8; ++i) acc[i] = bh;
    for (int k = 0; k < 256; k += 4) {
        floatx4 w4 = *(const floatx4*)&W[h * 256 + k];
#pragma unroll
        for (int i = 0; i < 8; ++i) {
            floatx4 x4 = *(const floatx4*)&xl[i * 256 + k];
            acc[i] += w4[0] * x4[0] + w4[1] * x4[1] + w4[2] * x4[2] + w4[3] * x4[3];
        }
    }
#pragma unroll
    for (int i = 0; i < 8; ++i) enc[(b0 + i) * 256 + h] = acc[i];
}

// ---------------------------------------------------------------------------
// genc[b][g] = b_ih[g]+b_hh[g] + sum_k enc[b][k] * W_ih[g][128+k]
__global__ void k_genc(const float* __restrict__ enc, const float* __restrict__ W_ih,
                       const float* __restrict__ b_ih, const float* __restrict__ b_hh,
                       float* __restrict__ genc) {
    __shared__ float el[8 * 256];
    const int bg = blockIdx.x >> 2;
    const int gc = blockIdx.x & 3;
    const int tid = threadIdx.x;
    const int b0 = bg * 8;
#pragma unroll
    for (int i = 0; i < 8; ++i) el[i * 256 + tid] = enc[(b0 + i) * 256 + tid];
    __syncthreads();
    const int g = gc * 256 + tid;
    float acc[8];
    const float bb = b_ih[g] + b_hh[g];
#pragma unroll
    for (int i = 0; i < 8; ++i) acc[i] = bb;
    for (int k = 0; k < 256; k += 4) {
        floatx4 w4 = *(const floatx4*)&W_ih[g * 384 + 128 + k];
#pragma unroll
        for (int i = 0; i < 8; ++i) {
            floatx4 e4 = *(const floatx4*)&el[i * 256 + k];
            acc[i] += w4[0] * e4[0] + w4[1] * e4[1] + w4[2] * e4[2] + w4[3] * e4[3];
        }
    }
#pragma unroll
    for (int i = 0; i < 8; ++i) genc[(b0 + i) * 1024 + g] = acc[i];
}

// ---------------------------------------------------------------------------
// embW[v][g] = sum_e emb[v][e] * W_ih[g][e]   (e < 128)
__global__ void k_embW(const float* __restrict__ emb, const float* __restrict__ W_ih,
                       float* __restrict__ embW) {
    __shared__ float el[128];
    const int v = blockIdx.x, tid = threadIdx.x;
    if (tid < 128) el[tid] = emb[v * 128 + tid];
    __syncthreads();
    float acc[4] = {0.f, 0.f, 0.f, 0.f};
    for (int k = 0; k < 128; k += 4) {
        floatx4 e4 = *(const floatx4*)&el[k];
#pragma unroll
        for (int j = 0; j < 4; ++j) {
            floatx4 w4 = *(const floatx4*)&W_ih[(tid + 256 * j) * 384 + k];
            acc[j] += w4[0] * e4[0] + w4[1] * e4[1] + w4[2] * e4[2] + w4[3] * e4[3];
        }
    }
#pragma unroll
    for (int j = 0; j < 4; ++j) embW[v * 1024 + tid + 256 * j] = acc[j];
}

// ---------------------------------------------------------------------------
// Cast W_hh / W_fc to bf16 in MFMA B-fragment order:
// frag[((nt*8+kt)*64+lane)*8 + j] = W[n = nt*16+(lane&15)][k = kt*32+(lane>>4)*8+j]
__global__ void k_frag(const float* __restrict__ W_hh, const float* __restrict__ W_fc,
                       short* __restrict__ whh_frag, short* __restrict__ wfc_frag) {
    const int idx = blockIdx.x * 256 + threadIdx.x;
    if (idx < 64 * 8 * 64) {
        const int l = idx & 63, kt = (idx >> 6) & 7, nt = idx >> 9;
        const int g = nt * 16 + (l & 15);
        const int kb = kt * 32 + (l >> 4) * 8;
        short8 o;
#pragma unroll
        for (int j = 0; j < 8; ++j) o[j] = f2bf(W_hh[g * 256 + kb + j]);
        *(short8*)(whh_frag + (size_t)idx * 8) = o;
    } else {
        const int i2 = idx - 64 * 8 * 64;
        if (i2 < NT_FC * 8 * 64) {
            const int l = i2 & 63, kt = (i2 >> 6) & 7, nt = i2 >> 9;
            const int v = nt * 16 + (l & 15);
            const int kb = kt * 32 + (l >> 4) * 8;
            short8 o;
#pragma unroll
            for (int j = 0; j < 8; ++j)
                o[j] = (v < VOC) ? f2bf(W_fc[v * 256 + kb + j]) : (short)0;
            *(short8*)(wfc_frag + (size_t)i2 * 8) = o;
        }
    }
}

// ---------------------------------------------------------------------------
// Zero the h-exchange buffer (1 MB) and the group flags (4 KB). Must run each
// launch (graph replay) because the flags are monotone within one run.
__global__ void k_zero(uint32_t* __restrict__ hx32, int* __restrict__ flags) {
    const int i = blockIdx.x * 256 + threadIdx.x;
    if (i < 262144) hx32[i] = 0;
    if (i < 1024) flags[i] = 0;
}

// ---------------------------------------------------------------------------
// Persistent LSTM, v2: weight-resident groups.
//   64 groups x 4 WGs (256 thr each) = 256 WGs, 1 per CU (128 KB LDS cap).
//   WG 'sub' of a group owns hidden units u in [sub*64, sub*64+64): its W_hh
//   rows {q*256+u} = 16 fragment tiles = 128 KB bf16, loaded into LDS ONCE
//   (99x reuse) -- removes the 512 KB/step/CU L2 weight stream that made each
//   step cost 9.9 us in the previous version.
//   h(t) is exchanged between the 4 WGs via a double-buffered global buffer in
//   A-fragment order + one monotone per-WG flag (agent-scope release/acquire).
//   Double buffering makes one flag/step sufficient: flags>=t proves all peers
//   finished READING parity (t-1)&1 == (t+1)&1 before we overwrite it.
__global__ __launch_bounds__(256, 1) void k_lstm2(
    const float* __restrict__ genc, const float* __restrict__ embW,
    const short* __restrict__ whh_frag, const int* __restrict__ targets,
    short* __restrict__ hs, short* __restrict__ hxch, int* __restrict__ flags) {
    __shared__ __align__(16) short wl[16 * 8 * 64 * 8];  // 128 KB: 16 tiles x 8KB
    const int tid = threadIdx.x;
    const int sub = blockIdx.x >> 6;   // 0..3: which hidden-unit slice
    const int grp = blockIdx.x & 63;   // batch group (16 rows)
    const int w = tid >> 6, lane = tid & 63;
    const int q16 = lane >> 4, l16 = lane & 15;

    // Stage this WG's W_hh slice into LDS: local tile lt=(q,ub) <- nt=q*16+sub*4+ub
#pragma unroll
    for (int lt = 0; lt < 16; ++lt) {
        const int q = lt >> 2, ub = lt & 3;
        const int nt = q * 16 + sub * 4 + ub;
        const short* src = whh_frag + (size_t)nt * 4096;
        short* dst = wl + lt * 4096;
        for (int i = tid; i < 512; i += 256)
            *(short8*)(dst + i * 8) = *(const short8*)(src + i * 8);
    }

    const int u = sub * 64 + w * 16 + l16;  // the ONE hidden unit this lane owns
    const int b0 = grp * 16;

    // t-invariant encoder gate bias, hoisted to registers (was 32 loads/step)
    float gec[4][4];
#pragma unroll
    for (int q = 0; q < 4; ++q)
#pragma unroll
        for (int r = 0; r < 4; ++r)
            gec[q][r] = genc[(size_t)(b0 + q16 * 4 + r) * GDIM + q * 256 + u];

    float c_state[4] = {0.f, 0.f, 0.f, 0.f};
    int tok[4];
#pragma unroll
    for (int r = 0; r < 4; ++r) tok[r] = targets[(b0 + q16 * 4 + r) * 100];

    int* const flg = flags + grp * 16;       // group's 4 flags in one 64B line
    short* const hxg = hxch + grp * 8192;    // 2 parities x 4096 shorts (8 KB each)

    __syncthreads();  // LDS weights ready

    for (int t = 0; t < TSEQ; ++t) {
        // prefetch next tokens + token gate bias (independent of h -> before poll)
        int tokn[4];
#pragma unroll
        for (int r = 0; r < 4; ++r)
            tokn[r] = targets[(b0 + q16 * 4 + r) * 100 + t + 1];
        float geW[4][4];
#pragma unroll
        for (int q = 0; q < 4; ++q)
#pragma unroll
            for (int r = 0; r < 4; ++r)
                geW[q][r] = embW[(size_t)tok[r] * GDIM + q * 256 + u];

        // wait until all 4 peers have published h(t)
        if (t > 0) {
            for (;;) {
                int f0 = __hip_atomic_load(flg + 0, __ATOMIC_RELAXED, __HIP_MEMORY_SCOPE_AGENT);
                int f1 = __hip_atomic_load(flg + 1, __ATOMIC_RELAXED, __HIP_MEMORY_SCOPE_AGENT);
                int f2 = __hip_atomic_load(flg + 2, __ATOMIC_RELAXED, __HIP_MEMORY_SCOPE_AGENT);
                int f3 = __hip_atomic_load(flg + 3, __ATOMIC_RELAXED, __HIP_MEMORY_SCOPE_AGENT);
                if (f0 >= t && f1 >= t && f2 >= t && f3 >= t) break;
            }
            acquire_fence_agent();
        }

        // A-fragments of full h(t): 8 coalesced 16B/lane loads from parity t&1
        const short* hx = hxg + (t & 1) * 4096;
        short8 afrag[8];
#pragma unroll
        for (int kt = 0; kt < 8; ++kt)
            afrag[kt] = *(const short8*)(hx + kt * 512 + lane * 8);

        // gates[16b x 64u x 4q] from LDS-resident weights; wave w owns ub=w,
        // 4 q-tiles -> i,f,g,o for the SAME u land fully in-lane.
        floatx4 acc[4];
#pragma unroll
        for (int q = 0; q < 4; ++q) {
            floatx4 a = {0.f, 0.f, 0.f, 0.f};
            const int lt = q * 4 + w;
#pragma unroll
            for (int kt = 0; kt < 8; ++kt) {
                short8 bf = *(const short8*)(wl + ((lt * 8 + kt) * 64 + lane) * 8);
                a = __builtin_amdgcn_mfma_f32_16x16x32_bf16(afrag[kt], bf, a, 0, 0, 0);
            }
            acc[q] = a;
        }

        // elementwise update; publish h(t+1) in A-frag order + hs for k_logits
        short* hn = hxg + ((t + 1) & 1) * 4096;
        const int ubase = (u >> 3) * 128 + (u & 7);
#pragma unroll
        for (int r = 0; r < 4; ++r) {
            float gi = acc[0][r] + gec[0][r] + geW[0][r];
            float gf = acc[1][r] + gec[1][r] + geW[1][r];
            float gg = acc[2][r] + gec[2][r] + geW[2][r];
            float go = acc[3][r] + gec[3][r] + geW[3][r];
            float i_ = sigm(gi), f_ = sigm(gf), g_ = tanh_fast(gg), o_ = sigm(go);
            float c = f_ * c_state[r] + i_ * g_;
            c_state[r] = c;
            float h = o_ * tanh_fast(c);
            short hv = f2bf(h);
            const int b = b0 + q16 * 4 + r;
            hn[ubase + (q16 * 4 + r) * 8] = hv;
            hs[((size_t)b * TSEQ + t) * HID + u] = hv;
        }
#pragma unroll
        for (int r = 0; r < 4; ++r) tok[r] = tokn[r];

        if (t < TSEQ - 1) {
            __threadfence();     // agent-scope release: make hn stores visible cross-XCD
            __syncthreads();     // all 4 waves' stores fenced before posting
            if (tid == 0)
                __hip_atomic_store(flg + sub, t + 1, __ATOMIC_RELEASE, __HIP_MEMORY_SCOPE_AGENT);
        }
    }
}

// ---------------------------------------------------------------------------
// logits[r][v] = b_fc[v] + sum_k hs[r][k] * W_fc[v][k], r = b*99+t
__global__ __launch_bounds__(256, 2) void k_logits(
    const short* __restrict__ hs, const short* __restrict__ wfc_frag,
    const float* __restrict__ b_fc, float* __restrict__ out) {
    const int tid = threadIdx.x;
    const int w = tid >> 6, lane = tid & 63;
    const int q16 = lane >> 4, l16 = lane & 15;
    const long mbase = (long)blockIdx.x * 64 + w * 16;

    short8 afrag[8];
#pragma unroll
    for (int kt = 0; kt < 8; ++kt)
        afrag[kt] = *(const short8*)(hs + (mbase + l16) * HID + kt * 32 + q16 * 8);

#pragma unroll 1
    for (int nt = 0; nt < NT_FC; ++nt) {
        floatx4 a = {0.f, 0.f, 0.f, 0.f};
#pragma unroll
        for (int kt = 0; kt < 8; ++kt) {
            short8 bfrag = *(const short8*)(wfc_frag + ((size_t)(nt * 8 + kt) * 64 + lane) * 8);
            a = __builtin_amdgcn_mfma_f32_16x16x32_bf16(afrag[kt], bfrag, a, 0, 0, 0);
        }
        const int v = nt * 16 + l16;
        if (v < VOC) {
            const float bias = b_fc[v];
#pragma unroll
            for (int r = 0; r < 4; ++r) {
                const long row = mbase + q16 * 4 + r;
                out[row * VOC + v] = a[r] + bias;
            }
        }
    }
}

// ---------------------------------------------------------------------------
extern "C" void kernel_launch(void* const* d_in, const int* in_sizes, int n_in,
                              void* d_out, int out_size, void* d_ws, size_t ws_size,
                              hipStream_t stream) {
    const float* encoder_out = (const float*)d_in[0];
    const int*   targets     = (const int*)d_in[1];
    const float* emb         = (const float*)d_in[2];
    const float* W_enc       = (const float*)d_in[3];
    const float* b_enc       = (const float*)d_in[4];
    const float* W_ih        = (const float*)d_in[5];
    const float* W_hh        = (const float*)d_in[6];
    const float* b_ih        = (const float*)d_in[7];
    const float* b_hh        = (const float*)d_in[8];
    const float* W_fc        = (const float*)d_in[9];
    const float* b_fc        = (const float*)d_in[10];
    float* out = (float*)d_out;

    char* ws = (char*)d_ws;
    float* enc      = (float*)(ws + 0);                    // 1,048,576 B (dead after k_genc)
    short* hxch     = (short*)(ws + 0);                    // reuses enc region: 1 MB
    float* genc     = (float*)(ws + 1048576);              // 4,194,304 B
    float* embW     = (float*)(ws + 5242880);              // 1,679,360 B
    short* whh_frag = (short*)(ws + 6922240);              //   524,288 B
    short* wfc_frag = (short*)(ws + 7446528);              //   212,992 B
    short* hs       = (short*)(ws + 7659520);              // 51,904,512 B
    int*   flags    = (int*)(ws + 59564032);               //     4,096 B

    k_enc<<<128, 256, 0, stream>>>(encoder_out, W_enc, b_enc, enc);
    k_genc<<<512, 256, 0, stream>>>(enc, W_ih, b_ih, b_hh, genc);
    k_zero<<<1024, 256, 0, stream>>>((uint32_t*)hxch, flags);   // after k_genc: enc region recycled
    k_embW<<<410, 256, 0, stream>>>(emb, W_ih, embW);
    k_frag<<<180, 256, 0, stream>>>(W_hh, W_fc, whh_frag, wfc_frag);

    {
        void* kargs[] = {&genc, &embW, &whh_frag, &targets, &hs, &hxch, &flags};
        hipError_t e = hipLaunchCooperativeKernel((const void*)k_lstm2, dim3(256), dim3(256),
                                                  kargs, 0, stream);
        if (e != hipSuccess)  // fallback: grid==CU count, 1 WG/CU -> de-facto co-resident
            k_lstm2<<<256, 256, 0, stream>>>(genc, embW, whh_frag, targets, hs, hxch, flags);
    }

    k_logits<<<1584, 256, 0, stream>>>(hs, wfc_frag, b_fc, out);
}

// Round 3
// 2243.708 us; speedup vs baseline: 1.8754x; 1.8754x over previous
//
#include <hip/hip_runtime.h>
#include <hip/hip_bf16.h>
#include <stdint.h>
#include <stddef.h>

// Problem dims
#define BATCH 1024
#define TSEQ  99      // SEQ_LEN-1 steps
#define HID   256
#define GDIM  1024    // 4*HID
#define EDIM  128
#define VOC   410
#define NT_FC 26      // ceil(410/16) -> padded 416

typedef __attribute__((ext_vector_type(8))) short short8;
typedef __attribute__((ext_vector_type(4))) float floatx4;

#define LOG2E 1.4426950408889634f

__device__ __forceinline__ short f2bf(float x) {
    union { float f; uint32_t u; } v; v.f = x;
    uint32_t r = (v.u + 0x7fffu + ((v.u >> 16) & 1u)) >> 16;
    return (short)r;
}

__device__ __forceinline__ float fexp2(float x) {
#if __has_builtin(__builtin_amdgcn_exp2f)
    return __builtin_amdgcn_exp2f(x);
#else
    return __exp2f(x);
#endif
}
__device__ __forceinline__ float frcp(float x) {
#if __has_builtin(__builtin_amdgcn_rcpf)
    return __builtin_amdgcn_rcpf(x);
#else
    return 1.f / x;
#endif
}
__device__ __forceinline__ float sigm(float x) {
    return frcp(1.f + fexp2(-LOG2E * x));
}
__device__ __forceinline__ float tanh_fast(float x) {
    x = fminf(fmaxf(x, -16.f), 16.f);
    float t = fexp2((2.f * LOG2E) * x);
    return (t - 1.f) * frcp(t + 1.f);
}

// ---------------------------------------------------------------------------
// enc[b][h] = b_enc[h] + sum_k encoder_out[b][k] * W_enc[h][k]
__global__ void k_enc(const float* __restrict__ x, const float* __restrict__ W,
                      const float* __restrict__ bias, float* __restrict__ enc) {
    __shared__ float xl[8 * 256];
    const int tid = threadIdx.x;
    const int b0 = blockIdx.x * 8;
#pragma unroll
    for (int i = 0; i < 8; ++i) xl[i * 256 + tid] = x[(b0 + i) * 256 + tid];
    __syncthreads();
    const int h = tid;
    float acc[8];
    const float bh = bias[h];
#pragma unroll
    for (int i = 0; i < 8; ++i) acc[i] = bh;
    for (int k = 0; k < 256; k += 4) {
        floatx4 w4 = *(const floatx4*)&W[h * 256 + k];
#pragma unroll
        for (int i = 0; i < 8; ++i) {
            floatx4 x4 = *(const floatx4*)&xl[i * 256 + k];
            acc[i] += w4[0] * x4[0] + w4[1] * x4[1] + w4[2] * x4[2] + w4[3] * x4[3];
        }
    }
#pragma unroll
    for (int i = 0; i < 8; ++i) enc[(b0 + i) * 256 + h] = acc[i];
}

// ---------------------------------------------------------------------------
// genc[b][g] = b_ih[g]+b_hh[g] + sum_k enc[b][k] * W_ih[g][128+k]
__global__ void k_genc(const float* __restrict__ enc, const float* __restrict__ W_ih,
                       const float* __restrict__ b_ih, const float* __restrict__ b_hh,
                       float* __restrict__ genc) {
    __shared__ float el[8 * 256];
    const int bg = blockIdx.x >> 2;
    const int gc = blockIdx.x & 3;
    const int tid = threadIdx.x;
    const int b0 = bg * 8;
#pragma unroll
    for (int i = 0; i < 8; ++i) el[i * 256 + tid] = enc[(b0 + i) * 256 + tid];
    __syncthreads();
    const int g = gc * 256 + tid;
    float acc[8];
    const float bb = b_ih[g] + b_hh[g];
#pragma unroll
    for (int i = 0; i < 8; ++i) acc[i] = bb;
    for (int k = 0; k < 256; k += 4) {
        floatx4 w4 = *(const floatx4*)&W_ih[g * 384 + 128 + k];
#pragma unroll
        for (int i = 0; i < 8; ++i) {
            floatx4 e4 = *(const floatx4*)&el[i * 256 + k];
            acc[i] += w4[0] * e4[0] + w4[1] * e4[1] + w4[2] * e4[2] + w4[3] * e4[3];
        }
    }
#pragma unroll
    for (int i = 0; i < 8; ++i) genc[(b0 + i) * 1024 + g] = acc[i];
}

// ---------------------------------------------------------------------------
// embW[v][g] = sum_e emb[v][e] * W_ih[g][e]   (e < 128)
__global__ void k_embW(const float* __restrict__ emb, const float* __restrict__ W_ih,
                       float* __restrict__ embW) {
    __shared__ float el[128];
    const int v = blockIdx.x, tid = threadIdx.x;
    if (tid < 128) el[tid] = emb[v * 128 + tid];
    __syncthreads();
    float acc[4] = {0.f, 0.f, 0.f, 0.f};
    for (int k = 0; k < 128; k += 4) {
        floatx4 e4 = *(const floatx4*)&el[k];
#pragma unroll
        for (int j = 0; j < 4; ++j) {
            floatx4 w4 = *(const floatx4*)&W_ih[(tid + 256 * j) * 384 + k];
            acc[j] += w4[0] * e4[0] + w4[1] * e4[1] + w4[2] * e4[2] + w4[3] * e4[3];
        }
    }
#pragma unroll
    for (int j = 0; j < 4; ++j) embW[v * 1024 + tid + 256 * j] = acc[j];
}

// ---------------------------------------------------------------------------
// Cast W_hh / W_fc to bf16 in MFMA B-fragment order:
// frag[((nt*8+kt)*64+lane)*8 + j] = W[n = nt*16+(lane&15)][k = kt*32+(lane>>4)*8+j]
__global__ void k_frag(const float* __restrict__ W_hh, const float* __restrict__ W_fc,
                       short* __restrict__ whh_frag, short* __restrict__ wfc_frag) {
    const int idx = blockIdx.x * 256 + threadIdx.x;
    if (idx < 64 * 8 * 64) {
        const int l = idx & 63, kt = (idx >> 6) & 7, nt = idx >> 9;
        const int g = nt * 16 + (l & 15);
        const int kb = kt * 32 + (l >> 4) * 8;
        short8 o;
#pragma unroll
        for (int j = 0; j < 8; ++j) o[j] = f2bf(W_hh[g * 256 + kb + j]);
        *(short8*)(whh_frag + (size_t)idx * 8) = o;
    } else {
        const int i2 = idx - 64 * 8 * 64;
        if (i2 < NT_FC * 8 * 64) {
            const int l = i2 & 63, kt = (i2 >> 6) & 7, nt = i2 >> 9;
            const int v = nt * 16 + (l & 15);
            const int kb = kt * 32 + (l >> 4) * 8;
            short8 o;
#pragma unroll
            for (int j = 0; j < 8; ++j)
                o[j] = (v < VOC) ? f2bf(W_fc[v * 256 + kb + j]) : (short)0;
            *(short8*)(wfc_frag + (size_t)i2 * 8) = o;
        }
    }
}

// ---------------------------------------------------------------------------
// Zero the stamped h-exchange buffer (2 MB = 524288 u32). Stamp 0 == valid
// h(0)=0 for step t=0. Must run each launch (stamps are monotone per run).
__global__ void k_zero(uint32_t* __restrict__ hx32) {
    const int i = blockIdx.x * 256 + threadIdx.x;
    if (i < 524288) hx32[i] = 0;
}

// ---------------------------------------------------------------------------
// Persistent LSTM, v3: weight-resident groups + FENCE-FREE stamped exchange.
//   64 groups x 4 WGs (256 thr) = 256 WGs, 1/CU (128 KB LDS for the W_hh
//   slice, loaded once, 99x reuse).
//   h exchange: each h value is a u32 word = (bf16 h << 16) | step_stamp,
//   double-buffered by step parity, accessed ONLY with relaxed agent-scope
//   atomics (cache-bypassing dword ops -- NO fences, NO L2 writebacks, which
//   is what made v2 4x slower). A reader spins until stamp == t; value and
//   stamp arrive atomically in one word, so no data/flag ordering is needed.
//   Overwrite safety (parity reuse at t+2): every reader is also a producer,
//   so A's h(t+2) write transitively happens-after every wave's h(t) reads
//   (A polled all of h(t+1); each wave published h(t+1) only after fully
//   reading h(t)). Waves are fully self-timed: no __syncthreads in the loop.
__global__ __launch_bounds__(256, 1) void k_lstm3(
    const float* __restrict__ genc, const float* __restrict__ embW,
    const short* __restrict__ whh_frag, const int* __restrict__ targets,
    short* __restrict__ hs, uint32_t* __restrict__ hxch) {
    __shared__ __align__(16) short wl[16 * 8 * 64 * 8];  // 128 KB: 16 tiles x 8KB
    const int tid = threadIdx.x;
    const int sub = blockIdx.x >> 6;   // 0..3: hidden-unit slice
    const int grp = blockIdx.x & 63;   // batch group (16 rows)
    const int w = tid >> 6, lane = tid & 63;
    const int q16 = lane >> 4, l16 = lane & 15;

    // Stage this WG's W_hh slice into LDS: local tile lt=(q,ub) <- nt=q*16+sub*4+ub
#pragma unroll
    for (int lt = 0; lt < 16; ++lt) {
        const int q = lt >> 2, ub = lt & 3;
        const int nt = q * 16 + sub * 4 + ub;
        const short* src = whh_frag + (size_t)nt * 4096;
        short* dst = wl + lt * 4096;
        for (int i = tid; i < 512; i += 256)
            *(short8*)(dst + i * 8) = *(const short8*)(src + i * 8);
    }

    const int u = sub * 64 + w * 16 + l16;  // the ONE hidden unit this lane owns
    const int b0 = grp * 16;

    // t-invariant encoder gate bias, hoisted to registers
    float gec[4][4];
#pragma unroll
    for (int q = 0; q < 4; ++q)
#pragma unroll
        for (int r = 0; r < 4; ++r)
            gec[q][r] = genc[(size_t)(b0 + q16 * 4 + r) * GDIM + q * 256 + u];

    float c_state[4] = {0.f, 0.f, 0.f, 0.f};
    int tok[4];
#pragma unroll
    for (int r = 0; r < 4; ++r) tok[r] = targets[(b0 + q16 * 4 + r) * 100];

    uint32_t* const hxg = hxch + grp * 8192;   // 2 parities x 4096 words
    const int ubase = (u >> 3) * 128 + (u & 7);

    __syncthreads();  // LDS weights ready (the ONLY barrier in this kernel)

    for (int t = 0; t < TSEQ; ++t) {
        // prefetch next tokens + token gate bias (independent of h -> pre-poll)
        int tokn[4];
#pragma unroll
        for (int r = 0; r < 4; ++r)
            tokn[r] = targets[(b0 + q16 * 4 + r) * 100 + t + 1];
        float geW[4][4];
#pragma unroll
        for (int q = 0; q < 4; ++q)
#pragma unroll
            for (int r = 0; r < 4; ++r)
                geW[q][r] = embW[(size_t)tok[r] * GDIM + q * 256 + u];

        // read full h(t): 64 stamped words/lane, issue all loads first
        const uint32_t* hx = hxg + (t & 1) * 4096;
        const uint32_t tt = (uint32_t)t;
        uint32_t wv[8][8];
#pragma unroll
        for (int kt = 0; kt < 8; ++kt)
#pragma unroll
            for (int j = 0; j < 8; ++j)
                wv[kt][j] = __hip_atomic_load(hx + kt * 512 + lane * 8 + j,
                                              __ATOMIC_RELAXED, __HIP_MEMORY_SCOPE_AGENT);
        short8 afrag[8];
#pragma unroll
        for (int kt = 0; kt < 8; ++kt) {
            for (;;) {
                uint32_t bad = 0;
#pragma unroll
                for (int j = 0; j < 8; ++j) bad |= (wv[kt][j] ^ tt);
                if ((bad & 0xffffu) == 0u) break;
#pragma unroll
                for (int j = 0; j < 8; ++j)
                    wv[kt][j] = __hip_atomic_load(hx + kt * 512 + lane * 8 + j,
                                                  __ATOMIC_RELAXED, __HIP_MEMORY_SCOPE_AGENT);
            }
            short8 a;
#pragma unroll
            for (int j = 0; j < 8; ++j) a[j] = (short)(wv[kt][j] >> 16);
            afrag[kt] = a;
        }

        // gates from LDS-resident weights; wave w owns its 16 units, 4 q-tiles
        // -> i,f,g,o for the SAME u land fully in-lane.
        floatx4 acc[4];
#pragma unroll
        for (int q = 0; q < 4; ++q) {
            floatx4 a = {0.f, 0.f, 0.f, 0.f};
            const int lt = q * 4 + w;
#pragma unroll
            for (int kt = 0; kt < 8; ++kt) {
                short8 bf = *(const short8*)(wl + ((lt * 8 + kt) * 64 + lane) * 8);
                a = __builtin_amdgcn_mfma_f32_16x16x32_bf16(afrag[kt], bf, a, 0, 0, 0);
            }
            acc[q] = a;
        }

        // elementwise update; publish stamped h(t+1), then hs for k_logits
        uint32_t* hn = hxg + ((t + 1) & 1) * 4096;
        const bool pub = (t < TSEQ - 1);
        const uint32_t stamp = (uint32_t)(t + 1);
#pragma unroll
        for (int r = 0; r < 4; ++r) {
            float gi = acc[0][r] + gec[0][r] + geW[0][r];
            float gf = acc[1][r] + gec[1][r] + geW[1][r];
            float gg = acc[2][r] + gec[2][r] + geW[2][r];
            float go = acc[3][r] + gec[3][r] + geW[3][r];
            float i_ = sigm(gi), f_ = sigm(gf), g_ = tanh_fast(gg), o_ = sigm(go);
            float c = f_ * c_state[r] + i_ * g_;
            c_state[r] = c;
            float h = o_ * tanh_fast(c);
            short hv = f2bf(h);
            if (pub)
                __hip_atomic_store(hn + ubase + (q16 * 4 + r) * 8,
                                   ((uint32_t)(uint16_t)hv << 16) | stamp,
                                   __ATOMIC_RELAXED, __HIP_MEMORY_SCOPE_AGENT);
            const int b = b0 + q16 * 4 + r;
            hs[((size_t)b * TSEQ + t) * HID + u] = hv;
        }
#pragma unroll
        for (int r = 0; r < 4; ++r) tok[r] = tokn[r];
    }
}

// ---------------------------------------------------------------------------
// logits[r][v] = b_fc[v] + sum_k hs[r][k] * W_fc[v][k], r = b*99+t
__global__ __launch_bounds__(256, 2) void k_logits(
    const short* __restrict__ hs, const short* __restrict__ wfc_frag,
    const float* __restrict__ b_fc, float* __restrict__ out) {
    const int tid = threadIdx.x;
    const int w = tid >> 6, lane = tid & 63;
    const int q16 = lane >> 4, l16 = lane & 15;
    const long mbase = (long)blockIdx.x * 64 + w * 16;

    short8 afrag[8];
#pragma unroll
    for (int kt = 0; kt < 8; ++kt)
        afrag[kt] = *(const short8*)(hs + (mbase + l16) * HID + kt * 32 + q16 * 8);

#pragma unroll 1
    for (int nt = 0; nt < NT_FC; ++nt) {
        floatx4 a = {0.f, 0.f, 0.f, 0.f};
#pragma unroll
        for (int kt = 0; kt < 8; ++kt) {
            short8 bfrag = *(const short8*)(wfc_frag + ((size_t)(nt * 8 + kt) * 64 + lane) * 8);
            a = __builtin_amdgcn_mfma_f32_16x16x32_bf16(afrag[kt], bfrag, a, 0, 0, 0);
        }
        const int v = nt * 16 + l16;
        if (v < VOC) {
            const float bias = b_fc[v];
#pragma unroll
            for (int r = 0; r < 4; ++r) {
                const long row = mbase + q16 * 4 + r;
                out[row * VOC + v] = a[r] + bias;
            }
        }
    }
}

// ---------------------------------------------------------------------------
extern "C" void kernel_launch(void* const* d_in, const int* in_sizes, int n_in,
                              void* d_out, int out_size, void* d_ws, size_t ws_size,
                              hipStream_t stream) {
    const float* encoder_out = (const float*)d_in[0];
    const int*   targets     = (const int*)d_in[1];
    const float* emb         = (const float*)d_in[2];
    const float* W_enc       = (const float*)d_in[3];
    const float* b_enc       = (const float*)d_in[4];
    const float* W_ih        = (const float*)d_in[5];
    const float* W_hh        = (const float*)d_in[6];
    const float* b_ih        = (const float*)d_in[7];
    const float* b_hh        = (const float*)d_in[8];
    const float* W_fc        = (const float*)d_in[9];
    const float* b_fc        = (const float*)d_in[10];
    float* out = (float*)d_out;

    char* ws = (char*)d_ws;
    float*    enc      = (float*)(ws + 0);           // 1,048,576 B
    float*    genc     = (float*)(ws + 1048576);     // 4,194,304 B
    float*    embW     = (float*)(ws + 5242880);     // 1,679,360 B
    short*    whh_frag = (short*)(ws + 6922240);     //   524,288 B
    short*    wfc_frag = (short*)(ws + 7446528);     //   212,992 B
    short*    hs       = (short*)(ws + 7659520);     // 51,904,512 B
    uint32_t* hxch     = (uint32_t*)(ws + 59564032); //  2,097,152 B (stamped h exchange)

    k_enc<<<128, 256, 0, stream>>>(encoder_out, W_enc, b_enc, enc);
    k_genc<<<512, 256, 0, stream>>>(enc, W_ih, b_ih, b_hh, genc);
    k_zero<<<2048, 256, 0, stream>>>(hxch);
    k_embW<<<410, 256, 0, stream>>>(emb, W_ih, embW);
    k_frag<<<180, 256, 0, stream>>>(W_hh, W_fc, whh_frag, wfc_frag);

    {
        void* kargs[] = {&genc, &embW, &whh_frag, &targets, &hs, &hxch};
        hipError_t e = hipLaunchCooperativeKernel((const void*)k_lstm3, dim3(256), dim3(256),
                                                  kargs, 0, stream);
        if (e != hipSuccess)  // fallback: grid==CU count, 1 WG/CU -> de-facto co-resident
            k_lstm3<<<256, 256, 0, stream>>>(genc, embW, whh_frag, targets, hs, hxch);
    }

    k_logits<<<1584, 256, 0, stream>>>(hs, wfc_frag, b_fc, out);
}

// Round 6
// 1044.774 us; speedup vs baseline: 4.0276x; 2.1476x over previous
//
#include <hip/hip_runtime.h>
#include <hip/hip_bf16.h>
#include <stdint.h>
#include <stddef.h>

// Problem dims
#define BATCH 1024
#define TSEQ  99      // SEQ_LEN-1 steps
#define HID   256
#define GDIM  1024    // 4*HID
#define EDIM  128
#define VOC   410
#define NT_FC 26      // ceil(410/16) -> padded 416

typedef __attribute__((ext_vector_type(8))) short short8;
typedef __attribute__((ext_vector_type(4))) float floatx4;
typedef __attribute__((ext_vector_type(4))) unsigned int uint4v;

#define LOG2E 1.4426950408889634f

__device__ __forceinline__ short f2bf(float x) {
    union { float f; uint32_t u; } v; v.f = x;
    uint32_t r = (v.u + 0x7fffu + ((v.u >> 16) & 1u)) >> 16;
    return (short)r;
}

__device__ __forceinline__ float fexp2(float x) {
#if __has_builtin(__builtin_amdgcn_exp2f)
    return __builtin_amdgcn_exp2f(x);
#else
    return __exp2f(x);
#endif
}
__device__ __forceinline__ float frcp(float x) {
#if __has_builtin(__builtin_amdgcn_rcpf)
    return __builtin_amdgcn_rcpf(x);
#else
    return 1.f / x;
#endif
}
__device__ __forceinline__ float sigm(float x) {
    return frcp(1.f + fexp2(-LOG2E * x));
}
__device__ __forceinline__ float tanh_fast(float x) {
    x = fminf(fmaxf(x, -16.f), 16.f);
    float t = fexp2((2.f * LOG2E) * x);
    return (t - 1.f) * frcp(t + 1.f);
}

// --- exchange-word loads: fast = volatile (sc0: bypass L1, read local L2);
//     slow = relaxed agent atomic (sc0 sc1: MALL, device coherence point) ---
__device__ __forceinline__ void frag_load_fast(uint4v& a, uint4v& b, const uint32_t* p) {
    a = *(volatile const uint4v*)(p);
    b = *(volatile const uint4v*)(p + 4);
}
__device__ __forceinline__ void frag_load_slow(uint4v& a, uint4v& b, const uint32_t* p) {
#pragma unroll
    for (int j = 0; j < 4; ++j)
        a[j] = __hip_atomic_load(p + j, __ATOMIC_RELAXED, __HIP_MEMORY_SCOPE_AGENT);
#pragma unroll
    for (int j = 0; j < 4; ++j)
        b[j] = __hip_atomic_load(p + 4 + j, __ATOMIC_RELAXED, __HIP_MEMORY_SCOPE_AGENT);
}

// ---------------------------------------------------------------------------
// enc[b][h] = b_enc[h] + sum_k encoder_out[b][k] * W_enc[h][k]
__global__ void k_enc(const float* __restrict__ x, const float* __restrict__ W,
                      const float* __restrict__ bias, float* __restrict__ enc) {
    __shared__ float xl[8 * 256];
    const int tid = threadIdx.x;
    const int b0 = blockIdx.x * 8;
#pragma unroll
    for (int i = 0; i < 8; ++i) xl[i * 256 + tid] = x[(b0 + i) * 256 + tid];
    __syncthreads();
    const int h = tid;
    float acc[8];
    const float bh = bias[h];
#pragma unroll
    for (int i = 0; i < 8; ++i) acc[i] = bh;
    for (int k = 0; k < 256; k += 4) {
        floatx4 w4 = *(const floatx4*)&W[h * 256 + k];
#pragma unroll
        for (int i = 0; i < 8; ++i) {
            floatx4 x4 = *(const floatx4*)&xl[i * 256 + k];
            acc[i] += w4[0] * x4[0] + w4[1] * x4[1] + w4[2] * x4[2] + w4[3] * x4[3];
        }
    }
#pragma unroll
    for (int i = 0; i < 8; ++i) enc[(b0 + i) * 256 + h] = acc[i];
}

// ---------------------------------------------------------------------------
// genc[b][g] = b_ih[g]+b_hh[g] + sum_k enc[b][k] * W_ih[g][128+k]
__global__ void k_genc(const float* __restrict__ enc, const float* __restrict__ W_ih,
                       const float* __restrict__ b_ih, const float* __restrict__ b_hh,
                       float* __restrict__ genc) {
    __shared__ float el[8 * 256];
    const int bg = blockIdx.x >> 2;
    const int gc = blockIdx.x & 3;
    const int tid = threadIdx.x;
    const int b0 = bg * 8;
#pragma unroll
    for (int i = 0; i < 8; ++i) el[i * 256 + tid] = enc[(b0 + i) * 256 + tid];
    __syncthreads();
    const int g = gc * 256 + tid;
    float acc[8];
    const float bb = b_ih[g] + b_hh[g];
#pragma unroll
    for (int i = 0; i < 8; ++i) acc[i] = bb;
    for (int k = 0; k < 256; k += 4) {
        floatx4 w4 = *(const floatx4*)&W_ih[g * 384 + 128 + k];
#pragma unroll
        for (int i = 0; i < 8; ++i) {
            floatx4 e4 = *(const floatx4*)&el[i * 256 + k];
            acc[i] += w4[0] * e4[0] + w4[1] * e4[1] + w4[2] * e4[2] + w4[3] * e4[3];
        }
    }
#pragma unroll
    for (int i = 0; i < 8; ++i) genc[(b0 + i) * 1024 + g] = acc[i];
}

// ---------------------------------------------------------------------------
// embW[v][g] = sum_e emb[v][e] * W_ih[g][e]   (e < 128)
__global__ void k_embW(const float* __restrict__ emb, const float* __restrict__ W_ih,
                       float* __restrict__ embW) {
    __shared__ float el[128];
    const int v = blockIdx.x, tid = threadIdx.x;
    if (tid < 128) el[tid] = emb[v * 128 + tid];
    __syncthreads();
    float acc[4] = {0.f, 0.f, 0.f, 0.f};
    for (int k = 0; k < 128; k += 4) {
        floatx4 e4 = *(const floatx4*)&el[k];
#pragma unroll
        for (int j = 0; j < 4; ++j) {
            floatx4 w4 = *(const floatx4*)&W_ih[(tid + 256 * j) * 384 + k];
            acc[j] += w4[0] * e4[0] + w4[1] * e4[1] + w4[2] * e4[2] + w4[3] * e4[3];
        }
    }
#pragma unroll
    for (int j = 0; j < 4; ++j) embW[v * 1024 + tid + 256 * j] = acc[j];
}

// ---------------------------------------------------------------------------
// Cast W_hh / W_fc to bf16 in MFMA B-fragment order:
// frag[((nt*8+kt)*64+lane)*8 + j] = W[n = nt*16+(lane&15)][k = kt*32+(lane>>4)*8+j]
__global__ void k_frag(const float* __restrict__ W_hh, const float* __restrict__ W_fc,
                       short* __restrict__ whh_frag, short* __restrict__ wfc_frag) {
    const int idx = blockIdx.x * 256 + threadIdx.x;
    if (idx < 64 * 8 * 64) {
        const int l = idx & 63, kt = (idx >> 6) & 7, nt = idx >> 9;
        const int g = nt * 16 + (l & 15);
        const int kb = kt * 32 + (l >> 4) * 8;
        short8 o;
#pragma unroll
        for (int j = 0; j < 8; ++j) o[j] = f2bf(W_hh[g * 256 + kb + j]);
        *(short8*)(whh_frag + (size_t)idx * 8) = o;
    } else {
        const int i2 = idx - 64 * 8 * 64;
        if (i2 < NT_FC * 8 * 64) {
            const int l = i2 & 63, kt = (i2 >> 6) & 7, nt = i2 >> 9;
            const int v = nt * 16 + (l & 15);
            const int kb = kt * 32 + (l >> 4) * 8;
            short8 o;
#pragma unroll
            for (int j = 0; j < 8; ++j)
                o[j] = (v < VOC) ? f2bf(W_fc[v * 256 + kb + j]) : (short)0;
            *(short8*)(wfc_frag + (size_t)i2 * 8) = o;
        }
    }
}

// ---------------------------------------------------------------------------
// Zero the stamped h-exchange buffer (2 MB = 524288 u32). Stamp 0 == valid
// h(0)=0 for step t=0. Plain stores: dispatch-end release + next dispatch's
// acquire make these visible everywhere (proven: v3's k_zero did the same and
// its MALL readers saw the zeros). Must run each launch (stamps monotone/run).
__global__ void k_zero(uint32_t* __restrict__ hx32) {
    const int i = blockIdx.x * 256 + threadIdx.x;
    if (i < 524288) hx32[i] = 0;
}

// ---------------------------------------------------------------------------
// Persistent LSTM, v5: weight-resident groups + self-healing dual-path
// stamped exchange (NO handshake, NO fences, NO inline asm).
//   64 groups x 4 WGs (256 thr) = 256 WGs, 1/CU; 128 KB W_hh slice in LDS
//   loaded once (kills v1's 512 KB/step/CU weight stream; FETCH 30.6->12.9MB
//   proven in r2). h exchange words = (bf16 h << 16) | step_stamp, double-
//   buffered by parity; stamp-match => value correct, no ordering needed.
//   PRODUCERS DUAL-PUBLISH each word: relaxed agent atomic (MALL authority,
//   v3-proven) THEN volatile store (sc0: local-L2 fast copy).
//   CONSUMERS poll volatile (local L2) first -- terminates at L2 latency when
//   the group shares an XCD (members {g,g+64,g+128,g+192} share bid%8 under
//   measured round-robin dispatch). After 4096 futile spins a consumer goes
//   sticky-slow (MALL polls, always terminate since MALL is always written).
//   => no placement assumption, no stale-line scenario, no codegen surprise
//   can hang; worst case is v3 speed. Fast case avoids v3's MALL round trips
//   (its 113 MB FETCH / 19.2 us/step cost).
__global__ __launch_bounds__(256, 1) void k_lstm5(
    const float* __restrict__ genc, const float* __restrict__ embW,
    const short* __restrict__ whh_frag, const int* __restrict__ targets,
    short* __restrict__ hs, uint32_t* __restrict__ hxch) {
    __shared__ __align__(16) short wl[16 * 8 * 64 * 8];  // 128 KB: 16 tiles x 8KB
    const int tid = threadIdx.x;
    const int sub = blockIdx.x >> 6;   // 0..3: hidden-unit slice
    const int grp = blockIdx.x & 63;   // batch group (16 rows)
    const int w = tid >> 6, lane = tid & 63;
    const int q16 = lane >> 4, l16 = lane & 15;

    // Stage this WG's W_hh slice into LDS: local tile lt=(q,ub) <- nt=q*16+sub*4+ub
#pragma unroll
    for (int lt = 0; lt < 16; ++lt) {
        const int q = lt >> 2, ub = lt & 3;
        const int nt = q * 16 + sub * 4 + ub;
        const short* src = whh_frag + (size_t)nt * 4096;
        short* dst = wl + lt * 4096;
        for (int i = tid; i < 512; i += 256)
            *(short8*)(dst + i * 8) = *(const short8*)(src + i * 8);
    }

    const int u = sub * 64 + w * 16 + l16;  // the ONE hidden unit this lane owns
    const int b0 = grp * 16;

    // t-invariant encoder gate bias, hoisted to registers
    float gec[4][4];
#pragma unroll
    for (int q = 0; q < 4; ++q)
#pragma unroll
        for (int r = 0; r < 4; ++r)
            gec[q][r] = genc[(size_t)(b0 + q16 * 4 + r) * GDIM + q * 256 + u];

    float c_state[4] = {0.f, 0.f, 0.f, 0.f};
    int tok[4];
#pragma unroll
    for (int r = 0; r < 4; ++r) tok[r] = targets[(b0 + q16 * 4 + r) * 100];

    uint32_t* const hxg = hxch + grp * 8192;   // 2 parities x 4096 words
    const int ubase = (u >> 3) * 128 + (u & 7);
    bool sticky = false;                        // escalated-to-MALL mode

    __syncthreads();  // LDS weights ready (the ONLY barrier in this kernel)

    for (int t = 0; t < TSEQ; ++t) {
        // prefetch next tokens + token gate bias (independent of h -> pre-poll)
        int tokn[4];
#pragma unroll
        for (int r = 0; r < 4; ++r)
            tokn[r] = targets[(b0 + q16 * 4 + r) * 100 + t + 1];
        float geW[4][4];
#pragma unroll
        for (int q = 0; q < 4; ++q)
#pragma unroll
            for (int r = 0; r < 4; ++r)
                geW[q][r] = embW[(size_t)tok[r] * GDIM + q * 256 + u];

        // read full h(t): 64 stamped words/lane from parity t&1
        const uint32_t* hx = hxg + (t & 1) * 4096;
        const uint32_t tt = (uint32_t)t;
        short8 afrag[8];
#pragma unroll
        for (int kt = 0; kt < 8; ++kt) {
            const uint32_t* p = hx + kt * 512 + lane * 8;
            uint4v a, b;
            if (!sticky) frag_load_fast(a, b, p); else frag_load_slow(a, b, p);
            int spins = 0;
            for (;;) {
                uint32_t bad = (a[0] ^ tt) | (a[1] ^ tt) | (a[2] ^ tt) | (a[3] ^ tt)
                             | (b[0] ^ tt) | (b[1] ^ tt) | (b[2] ^ tt) | (b[3] ^ tt);
                if ((bad & 0xffffu) == 0u) break;
                if (++spins > 4096) sticky = true;   // parachute: MALL always written
                if (!sticky) frag_load_fast(a, b, p); else frag_load_slow(a, b, p);
            }
            short8 f;
#pragma unroll
            for (int j = 0; j < 4; ++j) {
                f[j]     = (short)(a[j] >> 16);
                f[j + 4] = (short)(b[j] >> 16);
            }
            afrag[kt] = f;
        }

        // gates from LDS-resident weights; wave w owns its 16 units, 4 q-tiles
        // -> i,f,g,o for the SAME u land fully in-lane.
        floatx4 acc[4];
#pragma unroll
        for (int q = 0; q < 4; ++q) {
            floatx4 a = {0.f, 0.f, 0.f, 0.f};
            const int lt = q * 4 + w;
#pragma unroll
            for (int kt = 0; kt < 8; ++kt) {
                short8 bf = *(const short8*)(wl + ((lt * 8 + kt) * 64 + lane) * 8);
                a = __builtin_amdgcn_mfma_f32_16x16x32_bf16(afrag[kt], bf, a, 0, 0, 0);
            }
            acc[q] = a;
        }

        // elementwise update; dual-publish stamped h(t+1); hs for k_logits
        uint32_t* hn = hxg + ((t + 1) & 1) * 4096;
        const bool pub = (t < TSEQ - 1);
        const uint32_t stamp = (uint32_t)(t + 1);
#pragma unroll
        for (int r = 0; r < 4; ++r) {
            float gi = acc[0][r] + gec[0][r] + geW[0][r];
            float gf = acc[1][r] + gec[1][r] + geW[1][r];
            float gg = acc[2][r] + gec[2][r] + geW[2][r];
            float go = acc[3][r] + gec[3][r] + geW[3][r];
            float i_ = sigm(gi), f_ = sigm(gf), g_ = tanh_fast(gg), o_ = sigm(go);
            float c = f_ * c_state[r] + i_ * g_;
            c_state[r] = c;
            float h = o_ * tanh_fast(c);
            short hv = f2bf(h);
            if (pub) {
                uint32_t word = ((uint32_t)(uint16_t)hv << 16) | stamp;
                uint32_t* dst = hn + ubase + (q16 * 4 + r) * 8;
                // MALL authority first, then local-L2 fast copy (so a
                // write-through that invalidates the local line is re-dirtied)
                __hip_atomic_store(dst, word, __ATOMIC_RELAXED, __HIP_MEMORY_SCOPE_AGENT);
                *(volatile uint32_t*)dst = word;
            }
            const int b = b0 + q16 * 4 + r;
            hs[((size_t)b * TSEQ + t) * HID + u] = hv;
        }
#pragma unroll
        for (int r = 0; r < 4; ++r) tok[r] = tokn[r];
    }
}

// ---------------------------------------------------------------------------
// logits[r][v] = b_fc[v] + sum_k hs[r][k] * W_fc[v][k], r = b*99+t
__global__ __launch_bounds__(256, 2) void k_logits(
    const short* __restrict__ hs, const short* __restrict__ wfc_frag,
    const float* __restrict__ b_fc, float* __restrict__ out) {
    const int tid = threadIdx.x;
    const int w = tid >> 6, lane = tid & 63;
    const int q16 = lane >> 4, l16 = lane & 15;
    const long mbase = (long)blockIdx.x * 64 + w * 16;

    short8 afrag[8];
#pragma unroll
    for (int kt = 0; kt < 8; ++kt)
        afrag[kt] = *(const short8*)(hs + (mbase + l16) * HID + kt * 32 + q16 * 8);

#pragma unroll 1
    for (int nt = 0; nt < NT_FC; ++nt) {
        floatx4 a = {0.f, 0.f, 0.f, 0.f};
#pragma unroll
        for (int kt = 0; kt < 8; ++kt) {
            short8 bfrag = *(const short8*)(wfc_frag + ((size_t)(nt * 8 + kt) * 64 + lane) * 8);
            a = __builtin_amdgcn_mfma_f32_16x16x32_bf16(afrag[kt], bfrag, a, 0, 0, 0);
        }
        const int v = nt * 16 + l16;
        if (v < VOC) {
            const float bias = b_fc[v];
#pragma unroll
            for (int r = 0; r < 4; ++r) {
                const long row = mbase + q16 * 4 + r;
                out[row * VOC + v] = a[r] + bias;
            }
        }
    }
}

// ---------------------------------------------------------------------------
extern "C" void kernel_launch(void* const* d_in, const int* in_sizes, int n_in,
                              void* d_out, int out_size, void* d_ws, size_t ws_size,
                              hipStream_t stream) {
    const float* encoder_out = (const float*)d_in[0];
    const int*   targets     = (const int*)d_in[1];
    const float* emb         = (const float*)d_in[2];
    const float* W_enc       = (const float*)d_in[3];
    const float* b_enc       = (const float*)d_in[4];
    const float* W_ih        = (const float*)d_in[5];
    const float* W_hh        = (const float*)d_in[6];
    const float* b_ih        = (const float*)d_in[7];
    const float* b_hh        = (const float*)d_in[8];
    const float* W_fc        = (const float*)d_in[9];
    const float* b_fc        = (const float*)d_in[10];
    float* out = (float*)d_out;

    char* ws = (char*)d_ws;
    float*    enc      = (float*)(ws + 0);           // 1,048,576 B
    float*    genc     = (float*)(ws + 1048576);     // 4,194,304 B
    float*    embW     = (float*)(ws + 5242880);     // 1,679,360 B
    short*    whh_frag = (short*)(ws + 6922240);     //   524,288 B
    short*    wfc_frag = (short*)(ws + 7446528);     //   212,992 B
    short*    hs       = (short*)(ws + 7659520);     // 51,904,512 B
    uint32_t* hxch     = (uint32_t*)(ws + 59564032); //  2,097,152 B (stamped h exchange)

    k_enc<<<128, 256, 0, stream>>>(encoder_out, W_enc, b_enc, enc);
    k_genc<<<512, 256, 0, stream>>>(enc, W_ih, b_ih, b_hh, genc);
    k_zero<<<2048, 256, 0, stream>>>(hxch);
    k_embW<<<410, 256, 0, stream>>>(emb, W_ih, embW);
    k_frag<<<180, 256, 0, stream>>>(W_hh, W_fc, whh_frag, wfc_frag);

    {
        void* kargs[] = {&genc, &embW, &whh_frag, &targets, &hs, &hxch};
        hipError_t e = hipLaunchCooperativeKernel((const void*)k_lstm5, dim3(256), dim3(256),
                                                  kargs, 0, stream);
        if (e != hipSuccess)  // fallback: grid==CU count, 1 WG/CU -> de-facto co-resident
            k_lstm5<<<256, 256, 0, stream>>>(genc, embW, whh_frag, targets, hs, hxch);
    }

    k_logits<<<1584, 256, 0, stream>>>(hs, wfc_frag, b_fc, out);
}

// Round 7
// 1030.859 us; speedup vs baseline: 4.0819x; 1.0135x over previous
//
#include <hip/hip_runtime.h>
#include <hip/hip_bf16.h>
#include <stdint.h>
#include <stddef.h>

// Problem dims
#define BATCH 1024
#define TSEQ  99      // SEQ_LEN-1 steps
#define HID   256
#define GDIM  1024    // 4*HID
#define EDIM  128
#define VOC   410
#define NT_FC 26      // ceil(410/16) -> padded 416

typedef __attribute__((ext_vector_type(8))) short short8;
typedef __attribute__((ext_vector_type(4))) float floatx4;
typedef __attribute__((ext_vector_type(4))) unsigned int uint4v;

#define LOG2E 1.4426950408889634f

__device__ __forceinline__ short f2bf(float x) {
    union { float f; uint32_t u; } v; v.f = x;
    uint32_t r = (v.u + 0x7fffu + ((v.u >> 16) & 1u)) >> 16;
    return (short)r;
}

__device__ __forceinline__ float fexp2(float x) {
#if __has_builtin(__builtin_amdgcn_exp2f)
    return __builtin_amdgcn_exp2f(x);
#else
    return __exp2f(x);
#endif
}
__device__ __forceinline__ float frcp(float x) {
#if __has_builtin(__builtin_amdgcn_rcpf)
    return __builtin_amdgcn_rcpf(x);
#else
    return 1.f / x;
#endif
}
__device__ __forceinline__ float sigm(float x) {
    return frcp(1.f + fexp2(-LOG2E * x));
}
__device__ __forceinline__ float tanh_fast(float x) {
    x = fminf(fmaxf(x, -16.f), 16.f);
    float t = fexp2((2.f * LOG2E) * x);
    return (t - 1.f) * frcp(t + 1.f);
}

// --- exchange-word loads ----------------------------------------------------
// fast: volatile (sc0: bypass L1, read local L2 -- hits producer-dirtied lines
//       when the group shares an XCD; lines never invalidated because the
//       MALL-authority copy lives at DIFFERENT addresses)
// slow: relaxed agent atomic (sc0 sc1: MALL, device coherence point)
__device__ __forceinline__ void frag_load_fast(uint4v& a, uint4v& b, const uint32_t* p) {
    a = *(volatile const uint4v*)(p);
    b = *(volatile const uint4v*)(p + 4);
}
__device__ __forceinline__ void frag_load_slow(uint4v& a, uint4v& b, const uint32_t* p) {
#pragma unroll
    for (int j = 0; j < 4; ++j)
        a[j] = __hip_atomic_load(p + j, __ATOMIC_RELAXED, __HIP_MEMORY_SCOPE_AGENT);
#pragma unroll
    for (int j = 0; j < 4; ++j)
        b[j] = __hip_atomic_load(p + 4 + j, __ATOMIC_RELAXED, __HIP_MEMORY_SCOPE_AGENT);
}

// ---------------------------------------------------------------------------
// enc[b][h] = b_enc[h] + sum_k encoder_out[b][k] * W_enc[h][k]
__global__ void k_enc(const float* __restrict__ x, const float* __restrict__ W,
                      const float* __restrict__ bias, float* __restrict__ enc) {
    __shared__ float xl[8 * 256];
    const int tid = threadIdx.x;
    const int b0 = blockIdx.x * 8;
#pragma unroll
    for (int i = 0; i < 8; ++i) xl[i * 256 + tid] = x[(b0 + i) * 256 + tid];
    __syncthreads();
    const int h = tid;
    float acc[8];
    const float bh = bias[h];
#pragma unroll
    for (int i = 0; i < 8; ++i) acc[i] = bh;
    for (int k = 0; k < 256; k += 4) {
        floatx4 w4 = *(const floatx4*)&W[h * 256 + k];
#pragma unroll
        for (int i = 0; i < 8; ++i) {
            floatx4 x4 = *(const floatx4*)&xl[i * 256 + k];
            acc[i] += w4[0] * x4[0] + w4[1] * x4[1] + w4[2] * x4[2] + w4[3] * x4[3];
        }
    }
#pragma unroll
    for (int i = 0; i < 8; ++i) enc[(b0 + i) * 256 + h] = acc[i];
}

// ---------------------------------------------------------------------------
// genc[b][g] = b_ih[g]+b_hh[g] + sum_k enc[b][k] * W_ih[g][128+k]
__global__ void k_genc(const float* __restrict__ enc, const float* __restrict__ W_ih,
                       const float* __restrict__ b_ih, const float* __restrict__ b_hh,
                       float* __restrict__ genc) {
    __shared__ float el[8 * 256];
    const int bg = blockIdx.x >> 2;
    const int gc = blockIdx.x & 3;
    const int tid = threadIdx.x;
    const int b0 = bg * 8;
#pragma unroll
    for (int i = 0; i < 8; ++i) el[i * 256 + tid] = enc[(b0 + i) * 256 + tid];
    __syncthreads();
    const int g = gc * 256 + tid;
    float acc[8];
    const float bb = b_ih[g] + b_hh[g];
#pragma unroll
    for (int i = 0; i < 8; ++i) acc[i] = bb;
    for (int k = 0; k < 256; k += 4) {
        floatx4 w4 = *(const floatx4*)&W_ih[g * 384 + 128 + k];
#pragma unroll
        for (int i = 0; i < 8; ++i) {
            floatx4 e4 = *(const floatx4*)&el[i * 256 + k];
            acc[i] += w4[0] * e4[0] + w4[1] * e4[1] + w4[2] * e4[2] + w4[3] * e4[3];
        }
    }
#pragma unroll
    for (int i = 0; i < 8; ++i) genc[(b0 + i) * 1024 + g] = acc[i];
}

// ---------------------------------------------------------------------------
// embW[v][g] = sum_e emb[v][e] * W_ih[g][e]   (e < 128)
__global__ void k_embW(const float* __restrict__ emb, const float* __restrict__ W_ih,
                       float* __restrict__ embW) {
    __shared__ float el[128];
    const int v = blockIdx.x, tid = threadIdx.x;
    if (tid < 128) el[tid] = emb[v * 128 + tid];
    __syncthreads();
    float acc[4] = {0.f, 0.f, 0.f, 0.f};
    for (int k = 0; k < 128; k += 4) {
        floatx4 e4 = *(const floatx4*)&el[k];
#pragma unroll
        for (int j = 0; j < 4; ++j) {
            floatx4 w4 = *(const floatx4*)&W_ih[(tid + 256 * j) * 384 + k];
            acc[j] += w4[0] * e4[0] + w4[1] * e4[1] + w4[2] * e4[2] + w4[3] * e4[3];
        }
    }
#pragma unroll
    for (int j = 0; j < 4; ++j) embW[v * 1024 + tid + 256 * j] = acc[j];
}

// ---------------------------------------------------------------------------
// Cast W_hh / W_fc to bf16 in MFMA B-fragment order:
// frag[((nt*8+kt)*64+lane)*8 + j] = W[n = nt*16+(lane&15)][k = kt*32+(lane>>4)*8+j]
__global__ void k_frag(const float* __restrict__ W_hh, const float* __restrict__ W_fc,
                       short* __restrict__ whh_frag, short* __restrict__ wfc_frag) {
    const int idx = blockIdx.x * 256 + threadIdx.x;
    if (idx < 64 * 8 * 64) {
        const int l = idx & 63, kt = (idx >> 6) & 7, nt = idx >> 9;
        const int g = nt * 16 + (l & 15);
        const int kb = kt * 32 + (l >> 4) * 8;
        short8 o;
#pragma unroll
        for (int j = 0; j < 8; ++j) o[j] = f2bf(W_hh[g * 256 + kb + j]);
        *(short8*)(whh_frag + (size_t)idx * 8) = o;
    } else {
        const int i2 = idx - 64 * 8 * 64;
        if (i2 < NT_FC * 8 * 64) {
            const int l = i2 & 63, kt = (i2 >> 6) & 7, nt = i2 >> 9;
            const int v = nt * 16 + (l & 15);
            const int kb = kt * 32 + (l >> 4) * 8;
            short8 o;
#pragma unroll
            for (int j = 0; j < 8; ++j)
                o[j] = (v < VOC) ? f2bf(W_fc[v * 256 + kb + j]) : (short)0;
            *(short8*)(wfc_frag + (size_t)i2 * 8) = o;
        }
    }
}

// ---------------------------------------------------------------------------
// Zero BOTH stamped h-exchange buffers (fast + auth, 2 MB each). Stamp 0 ==
// valid h(0)=0 for step t=0. Plain stores: dispatch-end writeback makes the
// zeros visible to both sc0 (after fill) and sc1 readers (proven in v3/v5).
__global__ void k_zero(uint32_t* __restrict__ hxf, uint32_t* __restrict__ hxa) {
    const int i = blockIdx.x * 256 + threadIdx.x;
    if (i < 524288) { hxf[i] = 0; hxa[i] = 0; }
}

// ---------------------------------------------------------------------------
// Persistent LSTM, v6: weight-resident groups + DUAL-CHANNEL stamped exchange.
//   Structure as v5 (64 groups x 4 WGs, 128 KB W_hh slice in LDS loaded once;
//   stamped words (bf16 h << 16)|step, double-buffered by parity; no fences,
//   no loop barriers; sticky parachute -> cannot hang under any placement).
//   v5's residual cost (6.8us/step): its dual-publish wrote the MALL-authority
//   copy to the SAME address, invalidating the local-L2 line, so every poll
//   missed to MALL (FETCH 63MB = one fill per line per group-step), and polls
//   were issued per-kt -> 8 serialized MALL round trips per step.
//   v6 fixes both:
//     1. SEPARATE addresses: hx_fast (plain stores; stays dirty in the
//        group's local L2; polled with sc0 -> ~200cy hits) and hx_auth
//        (relaxed agent atomics to MALL; only read after 4096 futile spins).
//     2. All 16 poll loads issued in ONE batch before validation -> one
//        visibility latency per step, not eight.
__global__ __launch_bounds__(256, 1) void k_lstm6(
    const float* __restrict__ genc, const float* __restrict__ embW,
    const short* __restrict__ whh_frag, const int* __restrict__ targets,
    short* __restrict__ hs, uint32_t* __restrict__ hxf_g, uint32_t* __restrict__ hxa_g) {
    __shared__ __align__(16) short wl[16 * 8 * 64 * 8];  // 128 KB: 16 tiles x 8KB
    const int tid = threadIdx.x;
    const int sub = blockIdx.x >> 6;   // 0..3: hidden-unit slice
    const int grp = blockIdx.x & 63;   // batch group (16 rows)
    const int w = tid >> 6, lane = tid & 63;
    const int q16 = lane >> 4, l16 = lane & 15;

    // Stage this WG's W_hh slice into LDS: local tile lt=(q,ub) <- nt=q*16+sub*4+ub
#pragma unroll
    for (int lt = 0; lt < 16; ++lt) {
        const int q = lt >> 2, ub = lt & 3;
        const int nt = q * 16 + sub * 4 + ub;
        const short* src = whh_frag + (size_t)nt * 4096;
        short* dst = wl + lt * 4096;
        for (int i = tid; i < 512; i += 256)
            *(short8*)(dst + i * 8) = *(const short8*)(src + i * 8);
    }

    const int u = sub * 64 + w * 16 + l16;  // the ONE hidden unit this lane owns
    const int b0 = grp * 16;

    // t-invariant encoder gate bias, hoisted to registers
    float gec[4][4];
#pragma unroll
    for (int q = 0; q < 4; ++q)
#pragma unroll
        for (int r = 0; r < 4; ++r)
            gec[q][r] = genc[(size_t)(b0 + q16 * 4 + r) * GDIM + q * 256 + u];

    float c_state[4] = {0.f, 0.f, 0.f, 0.f};
    int tok[4];
#pragma unroll
    for (int r = 0; r < 4; ++r) tok[r] = targets[(b0 + q16 * 4 + r) * 100];

    uint32_t* const hxf = hxf_g + grp * 8192;   // fast: 2 parities x 4096 words
    uint32_t* const hxa = hxa_g + grp * 8192;   // auth: 2 parities x 4096 words
    const int ubase = (u >> 3) * 128 + (u & 7);
    bool sticky = false;                         // escalated-to-MALL mode

    __syncthreads();  // LDS weights ready (the ONLY barrier in this kernel)

    for (int t = 0; t < TSEQ; ++t) {
        // prefetch next tokens + token gate bias (independent of h -> pre-poll)
        int tokn[4];
#pragma unroll
        for (int r = 0; r < 4; ++r)
            tokn[r] = targets[(b0 + q16 * 4 + r) * 100 + t + 1];
        float geW[4][4];
#pragma unroll
        for (int q = 0; q < 4; ++q)
#pragma unroll
            for (int r = 0; r < 4; ++r)
                geW[q][r] = embW[(size_t)tok[r] * GDIM + q * 256 + u];

        // read full h(t) from parity t&1: issue ALL 16 fast loads first
        const uint32_t* hf = hxf + (t & 1) * 4096;
        const uint32_t* ha = hxa + (t & 1) * 4096;
        const uint32_t tt = (uint32_t)t;
        uint4v va[8], vb[8];
#pragma unroll
        for (int kt = 0; kt < 8; ++kt)
            frag_load_fast(va[kt], vb[kt], hf + kt * 512 + lane * 8);
        short8 afrag[8];
#pragma unroll
        for (int kt = 0; kt < 8; ++kt) {
            const uint32_t* pf = hf + kt * 512 + lane * 8;
            const uint32_t* pa = ha + kt * 512 + lane * 8;
            int spins = 0;
            for (;;) {
                uint32_t bad = (va[kt][0] ^ tt) | (va[kt][1] ^ tt)
                             | (va[kt][2] ^ tt) | (va[kt][3] ^ tt)
                             | (vb[kt][0] ^ tt) | (vb[kt][1] ^ tt)
                             | (vb[kt][2] ^ tt) | (vb[kt][3] ^ tt);
                if ((bad & 0xffffu) == 0u) break;
                if (++spins > 4096) sticky = true;   // parachute: MALL always written
                if (!sticky) frag_load_fast(va[kt], vb[kt], pf);
                else         frag_load_slow(va[kt], vb[kt], pa);
            }
            short8 f;
#pragma unroll
            for (int j = 0; j < 4; ++j) {
                f[j]     = (short)(va[kt][j] >> 16);
                f[j + 4] = (short)(vb[kt][j] >> 16);
            }
            afrag[kt] = f;
        }

        // gates from LDS-resident weights; wave w owns its 16 units, 4 q-tiles
        // -> i,f,g,o for the SAME u land fully in-lane.
        floatx4 acc[4];
#pragma unroll
        for (int q = 0; q < 4; ++q) {
            floatx4 a = {0.f, 0.f, 0.f, 0.f};
            const int lt = q * 4 + w;
#pragma unroll
            for (int kt = 0; kt < 8; ++kt) {
                short8 bf = *(const short8*)(wl + ((lt * 8 + kt) * 64 + lane) * 8);
                a = __builtin_amdgcn_mfma_f32_16x16x32_bf16(afrag[kt], bf, a, 0, 0, 0);
            }
            acc[q] = a;
        }

        // elementwise update; dual-channel publish of stamped h(t+1); hs write
        uint32_t* hnf = hxf + ((t + 1) & 1) * 4096;
        uint32_t* hna = hxa + ((t + 1) & 1) * 4096;
        const bool pub = (t < TSEQ - 1);
        const uint32_t stamp = (uint32_t)(t + 1);
#pragma unroll
        for (int r = 0; r < 4; ++r) {
            float gi = acc[0][r] + gec[0][r] + geW[0][r];
            float gf = acc[1][r] + gec[1][r] + geW[1][r];
            float gg = acc[2][r] + gec[2][r] + geW[2][r];
            float go = acc[3][r] + gec[3][r] + geW[3][r];
            float i_ = sigm(gi), f_ = sigm(gf), g_ = tanh_fast(gg), o_ = sigm(go);
            float c = f_ * c_state[r] + i_ * g_;
            c_state[r] = c;
            float h = o_ * tanh_fast(c);
            short hv = f2bf(h);
            if (pub) {
                uint32_t word = ((uint32_t)(uint16_t)hv << 16) | stamp;
                const int off = ubase + (q16 * 4 + r) * 8;
                *(volatile uint32_t*)(hnf + off) = word;   // fast: dirty local L2
                __hip_atomic_store(hna + off, word,        // auth: MALL, parachute
                                   __ATOMIC_RELAXED, __HIP_MEMORY_SCOPE_AGENT);
            }
            const int b = b0 + q16 * 4 + r;
            hs[((size_t)b * TSEQ + t) * HID + u] = hv;
        }
#pragma unroll
        for (int r = 0; r < 4; ++r) tok[r] = tokn[r];
    }
}

// ---------------------------------------------------------------------------
// logits[r][v] = b_fc[v] + sum_k hs[r][k] * W_fc[v][k], r = b*99+t
__global__ __launch_bounds__(256, 2) void k_logits(
    const short* __restrict__ hs, const short* __restrict__ wfc_frag,
    const float* __restrict__ b_fc, float* __restrict__ out) {
    const int tid = threadIdx.x;
    const int w = tid >> 6, lane = tid & 63;
    const int q16 = lane >> 4, l16 = lane & 15;
    const long mbase = (long)blockIdx.x * 64 + w * 16;

    short8 afrag[8];
#pragma unroll
    for (int kt = 0; kt < 8; ++kt)
        afrag[kt] = *(const short8*)(hs + (mbase + l16) * HID + kt * 32 + q16 * 8);

#pragma unroll 1
    for (int nt = 0; nt < NT_FC; ++nt) {
        floatx4 a = {0.f, 0.f, 0.f, 0.f};
#pragma unroll
        for (int kt = 0; kt < 8; ++kt) {
            short8 bfrag = *(const short8*)(wfc_frag + ((size_t)(nt * 8 + kt) * 64 + lane) * 8);
            a = __builtin_amdgcn_mfma_f32_16x16x32_bf16(afrag[kt], bfrag, a, 0, 0, 0);
        }
        const int v = nt * 16 + l16;
        if (v < VOC) {
            const float bias = b_fc[v];
#pragma unroll
            for (int r = 0; r < 4; ++r) {
                const long row = mbase + q16 * 4 + r;
                out[row * VOC + v] = a[r] + bias;
            }
        }
    }
}

// ---------------------------------------------------------------------------
extern "C" void kernel_launch(void* const* d_in, const int* in_sizes, int n_in,
                              void* d_out, int out_size, void* d_ws, size_t ws_size,
                              hipStream_t stream) {
    const float* encoder_out = (const float*)d_in[0];
    const int*   targets     = (const int*)d_in[1];
    const float* emb         = (const float*)d_in[2];
    const float* W_enc       = (const float*)d_in[3];
    const float* b_enc       = (const float*)d_in[4];
    const float* W_ih        = (const float*)d_in[5];
    const float* W_hh        = (const float*)d_in[6];
    const float* b_ih        = (const float*)d_in[7];
    const float* b_hh        = (const float*)d_in[8];
    const float* W_fc        = (const float*)d_in[9];
    const float* b_fc        = (const float*)d_in[10];
    float* out = (float*)d_out;

    char* ws = (char*)d_ws;
    float*    enc      = (float*)(ws + 0);           // 1,048,576 B
    float*    genc     = (float*)(ws + 1048576);     // 4,194,304 B
    float*    embW     = (float*)(ws + 5242880);     // 1,679,360 B
    short*    whh_frag = (short*)(ws + 6922240);     //   524,288 B
    short*    wfc_frag = (short*)(ws + 7446528);     //   212,992 B
    short*    hs       = (short*)(ws + 7659520);     // 51,904,512 B
    uint32_t* hxf      = (uint32_t*)(ws + 59564032); //  2,097,152 B (fast channel)
    uint32_t* hxa      = (uint32_t*)(ws + 61661184); //  2,097,152 B (auth channel)

    k_enc<<<128, 256, 0, stream>>>(encoder_out, W_enc, b_enc, enc);
    k_genc<<<512, 256, 0, stream>>>(enc, W_ih, b_ih, b_hh, genc);
    k_zero<<<2048, 256, 0, stream>>>(hxf, hxa);
    k_embW<<<410, 256, 0, stream>>>(emb, W_ih, embW);
    k_frag<<<180, 256, 0, stream>>>(W_hh, W_fc, whh_frag, wfc_frag);

    {
        void* kargs[] = {&genc, &embW, &whh_frag, &targets, &hs, &hxf, &hxa};
        hipError_t e = hipLaunchCooperativeKernel((const void*)k_lstm6, dim3(256), dim3(256),
                                                  kargs, 0, stream);
        if (e != hipSuccess)  // fallback: grid==CU count, 1 WG/CU -> de-facto co-resident
            k_lstm6<<<256, 256, 0, stream>>>(genc, embW, whh_frag, targets, hs, hxf, hxa);
    }

    k_logits<<<1584, 256, 0, stream>>>(hs, wfc_frag, b_fc, out);
}

// Round 8
// 642.056 us; speedup vs baseline: 6.5538x; 1.6056x over previous
//
#include <hip/hip_runtime.h>
#include <hip/hip_bf16.h>
#include <stdint.h>
#include <stddef.h>

// Problem dims
#define BATCH 1024
#define TSEQ  99      // SEQ_LEN-1 steps
#define HID   256
#define GDIM  1024    // 4*HID
#define EDIM  128
#define VOC   410
#define NT_FC 26      // ceil(410/16) -> padded 416

typedef __attribute__((ext_vector_type(8))) short short8;
typedef __attribute__((ext_vector_type(4))) float floatx4;

#define LOG2E 1.4426950408889634f

__device__ __forceinline__ short f2bf(float x) {
    union { float f; uint32_t u; } v; v.f = x;
    uint32_t r = (v.u + 0x7fffu + ((v.u >> 16) & 1u)) >> 16;
    return (short)r;
}

__device__ __forceinline__ float fexp2(float x) {
#if __has_builtin(__builtin_amdgcn_exp2f)
    return __builtin_amdgcn_exp2f(x);
#else
    return __exp2f(x);
#endif
}
__device__ __forceinline__ float frcp(float x) {
#if __has_builtin(__builtin_amdgcn_rcpf)
    return __builtin_amdgcn_rcpf(x);
#else
    return 1.f / x;
#endif
}
__device__ __forceinline__ float sigm(float x) {
    return frcp(1.f + fexp2(-LOG2E * x));
}
__device__ __forceinline__ float tanh_fast(float x) {
    x = fminf(fmaxf(x, -16.f), 16.f);
    float t = fexp2((2.f * LOG2E) * x);
    return (t - 1.f) * frcp(t + 1.f);
}

__device__ __forceinline__ uint32_t ld_mall(const uint32_t* p) {
    return __hip_atomic_load(p, __ATOMIC_RELAXED, __HIP_MEMORY_SCOPE_AGENT);
}
__device__ __forceinline__ void st_mall(uint32_t* p, uint32_t v) {
    __hip_atomic_store(p, v, __ATOMIC_RELAXED, __HIP_MEMORY_SCOPE_AGENT);
}

// ---------------------------------------------------------------------------
// enc[b][h] = b_enc[h] + sum_k encoder_out[b][k] * W_enc[h][k]
__global__ void k_enc(const float* __restrict__ x, const float* __restrict__ W,
                      const float* __restrict__ bias, float* __restrict__ enc) {
    __shared__ float xl[8 * 256];
    const int tid = threadIdx.x;
    const int b0 = blockIdx.x * 8;
#pragma unroll
    for (int i = 0; i < 8; ++i) xl[i * 256 + tid] = x[(b0 + i) * 256 + tid];
    __syncthreads();
    const int h = tid;
    float acc[8];
    const float bh = bias[h];
#pragma unroll
    for (int i = 0; i < 8; ++i) acc[i] = bh;
    for (int k = 0; k < 256; k += 4) {
        floatx4 w4 = *(const floatx4*)&W[h * 256 + k];
#pragma unroll
        for (int i = 0; i < 8; ++i) {
            floatx4 x4 = *(const floatx4*)&xl[i * 256 + k];
            acc[i] += w4[0] * x4[0] + w4[1] * x4[1] + w4[2] * x4[2] + w4[3] * x4[3];
        }
    }
#pragma unroll
    for (int i = 0; i < 8; ++i) enc[(b0 + i) * 256 + h] = acc[i];
}

// ---------------------------------------------------------------------------
// genc[b][g] = b_ih[g]+b_hh[g] + sum_k enc[b][k] * W_ih[g][128+k]
__global__ void k_genc(const float* __restrict__ enc, const float* __restrict__ W_ih,
                       const float* __restrict__ b_ih, const float* __restrict__ b_hh,
                       float* __restrict__ genc) {
    __shared__ float el[8 * 256];
    const int bg = blockIdx.x >> 2;
    const int gc = blockIdx.x & 3;
    const int tid = threadIdx.x;
    const int b0 = bg * 8;
#pragma unroll
    for (int i = 0; i < 8; ++i) el[i * 256 + tid] = enc[(b0 + i) * 256 + tid];
    __syncthreads();
    const int g = gc * 256 + tid;
    float acc[8];
    const float bb = b_ih[g] + b_hh[g];
#pragma unroll
    for (int i = 0; i < 8; ++i) acc[i] = bb;
    for (int k = 0; k < 256; k += 4) {
        floatx4 w4 = *(const floatx4*)&W_ih[g * 384 + 128 + k];
#pragma unroll
        for (int i = 0; i < 8; ++i) {
            floatx4 e4 = *(const floatx4*)&el[i * 256 + k];
            acc[i] += w4[0] * e4[0] + w4[1] * e4[1] + w4[2] * e4[2] + w4[3] * e4[3];
        }
    }
#pragma unroll
    for (int i = 0; i < 8; ++i) genc[(b0 + i) * 1024 + g] = acc[i];
}

// ---------------------------------------------------------------------------
// embW[v][g] = sum_e emb[v][e] * W_ih[g][e]   (e < 128)
__global__ void k_embW(const float* __restrict__ emb, const float* __restrict__ W_ih,
                       float* __restrict__ embW) {
    __shared__ float el[128];
    const int v = blockIdx.x, tid = threadIdx.x;
    if (tid < 128) el[tid] = emb[v * 128 + tid];
    __syncthreads();
    float acc[4] = {0.f, 0.f, 0.f, 0.f};
    for (int k = 0; k < 128; k += 4) {
        floatx4 e4 = *(const floatx4*)&el[k];
#pragma unroll
        for (int j = 0; j < 4; ++j) {
            floatx4 w4 = *(const floatx4*)&W_ih[(tid + 256 * j) * 384 + k];
            acc[j] += w4[0] * e4[0] + w4[1] * e4[1] + w4[2] * e4[2] + w4[3] * e4[3];
        }
    }
#pragma unroll
    for (int j = 0; j < 4; ++j) embW[v * 1024 + tid + 256 * j] = acc[j];
}

// ---------------------------------------------------------------------------
// Cast W_hh / W_fc to bf16 in MFMA B-fragment order:
// frag[((nt*8+kt)*64+lane)*8 + j] = W[n = nt*16+(lane&15)][k = kt*32+(lane>>4)*8+j]
__global__ void k_frag(const float* __restrict__ W_hh, const float* __restrict__ W_fc,
                       short* __restrict__ whh_frag, short* __restrict__ wfc_frag) {
    const int idx = blockIdx.x * 256 + threadIdx.x;
    if (idx < 64 * 8 * 64) {
        const int l = idx & 63, kt = (idx >> 6) & 7, nt = idx >> 9;
        const int g = nt * 16 + (l & 15);
        const int kb = kt * 32 + (l >> 4) * 8;
        short8 o;
#pragma unroll
        for (int j = 0; j < 8; ++j) o[j] = f2bf(W_hh[g * 256 + kb + j]);
        *(short8*)(whh_frag + (size_t)idx * 8) = o;
    } else {
        const int i2 = idx - 64 * 8 * 64;
        if (i2 < NT_FC * 8 * 64) {
            const int l = i2 & 63, kt = (i2 >> 6) & 7, nt = i2 >> 9;
            const int v = nt * 16 + (l & 15);
            const int kb = kt * 32 + (l >> 4) * 8;
            short8 o;
#pragma unroll
            for (int j = 0; j < 8; ++j)
                o[j] = (v < VOC) ? f2bf(W_fc[v * 256 + kb + j]) : (short)0;
            *(short8*)(wfc_frag + (size_t)i2 * 8) = o;
        }
    }
}

// ---------------------------------------------------------------------------
// Zero exchange data (262144 u32 = 1 MB: 64 groups x 2 parities x 2048 words,
// packed 2xbf16 -> h(0)=0 for step 0) and flags (512 u32; flag slot value 0
// == "step 0 data valid"). Must run each launch (flags monotone per run).
__global__ void k_zero(uint32_t* __restrict__ ex, uint32_t* __restrict__ flags) {
    const int i = blockIdx.x * 256 + threadIdx.x;
    if (i < 262144) ex[i] = 0;
    if (i < 512) flags[i] = 0;
}

// ---------------------------------------------------------------------------
// Persistent LSTM, v7: weight-resident groups + FLAG-GATED MALL exchange.
//   64 groups x 4 WGs x 256 thr; 128 KB W_hh slice in LDS loaded once
//   (proven: FETCH 30.6->12.9 MB). v5/v6 lesson: HIP volatile == sc0 sc1, so
//   every "fast" poll was a MALL round trip, serialized per-kt (6.7us/step).
//   v7 pays MALL latency ONCE per step:
//     producer: 2 packed relaxed stores/thread (8 KB/group, no stamps)
//               -> __syncthreads (drains vmcnt(0) for ALL threads' stores --
//               m97-documented barrier semantics) -> tid0 stores flag = t+1.
//     consumer: polls the 4 flags (one 16B line, same-address lanes merge ->
//               negligible traffic) until all >= t; compiler barrier; ONE
//               batched 8-load read staged into LDS (4 WG reads, not 16 wave
//               reads); __syncthreads; conflict-free ds_read_b128 fragments.
//   Real-time ordering without fences: B's data loads complete before B's
//   flag reaches MALL (barrier drain), which A observes before A's overwrite
//   reaches MALL. Flags published unconditionally -> no spin can hang.
__global__ __launch_bounds__(256, 1) void k_lstm7(
    const float* __restrict__ genc, const float* __restrict__ embW,
    const short* __restrict__ whh_frag, const int* __restrict__ targets,
    short* __restrict__ hs, uint32_t* __restrict__ exch, uint32_t* __restrict__ flags) {
    __shared__ __align__(16) short wl[16 * 8 * 64 * 8];  // 128 KB: 16 tiles x 8KB
    __shared__ __align__(16) short hld[2][4096];         // 16 KB: h staging, A-frag order
    const int tid = threadIdx.x;
    const int sub = blockIdx.x >> 6;   // 0..3: hidden-unit slice
    const int grp = blockIdx.x & 63;   // batch group (16 rows)
    const int w = tid >> 6, lane = tid & 63;
    const int q16 = lane >> 4, l16 = lane & 15;

    // Stage this WG's W_hh slice into LDS: local tile lt=(q,ub) <- nt=q*16+sub*4+ub
#pragma unroll
    for (int lt = 0; lt < 16; ++lt) {
        const int q = lt >> 2, ub = lt & 3;
        const int nt = q * 16 + sub * 4 + ub;
        const short* src = whh_frag + (size_t)nt * 4096;
        short* dst = wl + lt * 4096;
        for (int i = tid; i < 512; i += 256)
            *(short8*)(dst + i * 8) = *(const short8*)(src + i * 8);
    }

    const int u = sub * 64 + w * 16 + l16;  // the ONE hidden unit this lane owns
    const int b0 = grp * 16;

    // t-invariant encoder gate bias, hoisted to registers
    float gec[4][4];
#pragma unroll
    for (int q = 0; q < 4; ++q)
#pragma unroll
        for (int r = 0; r < 4; ++r)
            gec[q][r] = genc[(size_t)(b0 + q16 * 4 + r) * GDIM + q * 256 + u];

    float c_state[4] = {0.f, 0.f, 0.f, 0.f};
    int tok[4];
#pragma unroll
    for (int r = 0; r < 4; ++r) tok[r] = targets[(b0 + q16 * 4 + r) * 100];

    uint32_t* const exg = exch + grp * 4096;   // 2 parities x 2048 packed words
    uint32_t* const flg = flags + grp * 8;     // 2 parities x 4 flags

    __syncthreads();  // LDS weights ready

    for (int t = 0; t < TSEQ; ++t) {
        const int p = t & 1;
        // prefetch next tokens + token gate bias (independent of h -> pre-poll)
        int tokn[4];
#pragma unroll
        for (int r = 0; r < 4; ++r)
            tokn[r] = targets[(b0 + q16 * 4 + r) * 100 + t + 1];
        float geW[4][4];
#pragma unroll
        for (int q = 0; q < 4; ++q)
#pragma unroll
            for (int r = 0; r < 4; ++r)
                geW[q][r] = embW[(size_t)tok[r] * GDIM + q * 256 + u];

        // ---- poll the 4 producer flags for step t (parity p) ----
        const uint32_t tt = (uint32_t)t;
        for (;;) {
            uint32_t f0 = ld_mall(flg + p * 4 + 0);
            uint32_t f1 = ld_mall(flg + p * 4 + 1);
            uint32_t f2 = ld_mall(flg + p * 4 + 2);
            uint32_t f3 = ld_mall(flg + p * 4 + 3);
            if (f0 >= tt && f1 >= tt && f2 >= tt && f3 >= tt) break;
        }
        asm volatile("" ::: "memory");  // keep data loads below the poll

        // ---- one batched read of h(t) (8 coalesced dwords/thread) -> LDS ----
        const uint32_t* exp_ = exg + p * 2048;
        uint32_t wv[8];
#pragma unroll
        for (int i = 0; i < 8; ++i) wv[i] = ld_mall(exp_ + tid + 256 * i);
#pragma unroll
        for (int i = 0; i < 8; ++i) {
            const int wi = tid + 256 * i;
            const int uu = wi >> 3, rem = wi & 7;
            const int row0 = (rem >> 1) * 4 + (rem & 1) * 2;
            const int base = (uu >> 3) * 128 + (uu & 7);
            hld[p][base + row0 * 8] = (short)(wv[i] & 0xffffu);
            hld[p][base + (row0 + 1) * 8] = (short)(wv[i] >> 16);
        }
        __syncthreads();  // staging complete before fragment reads

        // A-fragments: conflict-free ds_read_b128
        short8 afrag[8];
#pragma unroll
        for (int kt = 0; kt < 8; ++kt)
            afrag[kt] = *(const short8*)&hld[p][kt * 512 + lane * 8];

        // gates from LDS-resident weights; wave w owns its 16 units, 4 q-tiles
        floatx4 acc[4];
#pragma unroll
        for (int q = 0; q < 4; ++q) {
            floatx4 a = {0.f, 0.f, 0.f, 0.f};
            const int lt = q * 4 + w;
#pragma unroll
            for (int kt = 0; kt < 8; ++kt) {
                short8 bf = *(const short8*)(wl + ((lt * 8 + kt) * 64 + lane) * 8);
                a = __builtin_amdgcn_mfma_f32_16x16x32_bf16(afrag[kt], bf, a, 0, 0, 0);
            }
            acc[q] = a;
        }

        // elementwise update; publish packed h(t+1); hs write for k_logits
        short hv[4];
#pragma unroll
        for (int r = 0; r < 4; ++r) {
            float gi = acc[0][r] + gec[0][r] + geW[0][r];
            float gf = acc[1][r] + gec[1][r] + geW[1][r];
            float gg = acc[2][r] + gec[2][r] + geW[2][r];
            float go = acc[3][r] + gec[3][r] + geW[3][r];
            float i_ = sigm(gi), f_ = sigm(gf), g_ = tanh_fast(gg), o_ = sigm(go);
            float c = f_ * c_state[r] + i_ * g_;
            c_state[r] = c;
            float h = o_ * tanh_fast(c);
            hv[r] = f2bf(h);
            const int b = b0 + q16 * 4 + r;
            hs[((size_t)b * TSEQ + t) * HID + u] = hv[r];
        }
        if (t < TSEQ - 1) {
            uint32_t* exn = exg + (p ^ 1) * 2048;
            uint32_t w0 = (uint32_t)(uint16_t)hv[0] | ((uint32_t)(uint16_t)hv[1] << 16);
            uint32_t w1 = (uint32_t)(uint16_t)hv[2] | ((uint32_t)(uint16_t)hv[3] << 16);
            st_mall(exn + u * 8 + q16 * 2, w0);
            st_mall(exn + u * 8 + q16 * 2 + 1, w1);
            __syncthreads();  // drains ALL threads' stores (vmcnt(0)) pre-flag
            if (tid == 0) st_mall(flg + (p ^ 1) * 4 + sub, (uint32_t)(t + 1));
        }
#pragma unroll
        for (int r = 0; r < 4; ++r) tok[r] = tokn[r];
    }
}

// ---------------------------------------------------------------------------
// logits[r][v] = b_fc[v] + sum_k hs[r][k] * W_fc[v][k], r = b*99+t
__global__ __launch_bounds__(256, 2) void k_logits(
    const short* __restrict__ hs, const short* __restrict__ wfc_frag,
    const float* __restrict__ b_fc, float* __restrict__ out) {
    const int tid = threadIdx.x;
    const int w = tid >> 6, lane = tid & 63;
    const int q16 = lane >> 4, l16 = lane & 15;
    const long mbase = (long)blockIdx.x * 64 + w * 16;

    short8 afrag[8];
#pragma unroll
    for (int kt = 0; kt < 8; ++kt)
        afrag[kt] = *(const short8*)(hs + (mbase + l16) * HID + kt * 32 + q16 * 8);

#pragma unroll 1
    for (int nt = 0; nt < NT_FC; ++nt) {
        floatx4 a = {0.f, 0.f, 0.f, 0.f};
#pragma unroll
        for (int kt = 0; kt < 8; ++kt) {
            short8 bfrag = *(const short8*)(wfc_frag + ((size_t)(nt * 8 + kt) * 64 + lane) * 8);
            a = __builtin_amdgcn_mfma_f32_16x16x32_bf16(afrag[kt], bfrag, a, 0, 0, 0);
        }
        const int v = nt * 16 + l16;
        if (v < VOC) {
            const float bias = b_fc[v];
#pragma unroll
            for (int r = 0; r < 4; ++r) {
                const long row = mbase + q16 * 4 + r;
                out[row * VOC + v] = a[r] + bias;
            }
        }
    }
}

// ---------------------------------------------------------------------------
extern "C" void kernel_launch(void* const* d_in, const int* in_sizes, int n_in,
                              void* d_out, int out_size, void* d_ws, size_t ws_size,
                              hipStream_t stream) {
    const float* encoder_out = (const float*)d_in[0];
    const int*   targets     = (const int*)d_in[1];
    const float* emb         = (const float*)d_in[2];
    const float* W_enc       = (const float*)d_in[3];
    const float* b_enc       = (const float*)d_in[4];
    const float* W_ih        = (const float*)d_in[5];
    const float* W_hh        = (const float*)d_in[6];
    const float* b_ih        = (const float*)d_in[7];
    const float* b_hh        = (const float*)d_in[8];
    const float* W_fc        = (const float*)d_in[9];
    const float* b_fc        = (const float*)d_in[10];
    float* out = (float*)d_out;

    char* ws = (char*)d_ws;
    float*    enc      = (float*)(ws + 0);           // 1,048,576 B
    float*    genc     = (float*)(ws + 1048576);     // 4,194,304 B
    float*    embW     = (float*)(ws + 5242880);     // 1,679,360 B
    short*    whh_frag = (short*)(ws + 6922240);     //   524,288 B
    short*    wfc_frag = (short*)(ws + 7446528);     //   212,992 B
    short*    hs       = (short*)(ws + 7659520);     // 51,904,512 B
    uint32_t* exch     = (uint32_t*)(ws + 59564032); //  1,048,576 B (packed h exchange)
    uint32_t* flags    = (uint32_t*)(ws + 60612608); //      2,048 B

    k_enc<<<128, 256, 0, stream>>>(encoder_out, W_enc, b_enc, enc);
    k_genc<<<512, 256, 0, stream>>>(enc, W_ih, b_ih, b_hh, genc);
    k_zero<<<1024, 256, 0, stream>>>(exch, flags);
    k_embW<<<410, 256, 0, stream>>>(emb, W_ih, embW);
    k_frag<<<180, 256, 0, stream>>>(W_hh, W_fc, whh_frag, wfc_frag);

    {
        void* kargs[] = {&genc, &embW, &whh_frag, &targets, &hs, &exch, &flags};
        hipError_t e = hipLaunchCooperativeKernel((const void*)k_lstm7, dim3(256), dim3(256),
                                                  kargs, 0, stream);
        if (e != hipSuccess)  // fallback: grid==CU count, 1 WG/CU -> de-facto co-resident
            k_lstm7<<<256, 256, 0, stream>>>(genc, embW, whh_frag, targets, hs, exch, flags);
    }

    k_logits<<<1584, 256, 0, stream>>>(hs, wfc_frag, b_fc, out);
}